// Round 6
// baseline (453.597 us; speedup 1.0000x reference)
//
#include <hip/hip_runtime.h>

#define DD 2048
#define EE 64
#define NROWS 32768
#define BR 128            // rows per block
#define ROUNDS 64         // 512 k per quarter / 8 k per round

// Block: 128 rows x 64 experts, 512 threads.
// thread t -> (rg = t>>5 [0..15], eg = (t>>2)&7 [0..7], kq = t&3 [0..3])
// Each thread: 8x8 micro-tile (rows rg*8.., experts eg*8..) over K-quarter kq.
// Per round each quarter stages 8 k-floats (2 float4 chunks) for all rows/exps.
// LDS layout (per buffer, 6144 floats = 24KB): x[128 rows][8 chunks], then
// w[64 exps][8 chunks]; logical chunk c (= kq*2+k4) of row r stored at
// position c ^ ((r>>3)&7)  (x)  /  c ^ (e>>3)  (w). Written linearly by
// global_load_lds from a pre-swizzled global source; de-swizzled on read.
__global__ __launch_bounds__(512, 2) void router_main(const float* __restrict__ x,
                                                      const float* __restrict__ W,
                                                      float* __restrict__ out,
                                                      float* __restrict__ accum) {
    __shared__ __align__(16) float smem[12288];   // 48 KB (staging; epilogue overlays)

    const int t  = threadIdx.x;
    const int kq = t & 3;
    const int eg = (t >> 2) & 7;
    const int rg = t >> 5;
    const int row0 = blockIdx.x * BR;

    const char* xc = (const char*)x;
    const char* wc = (const char*)W;

    // ---- staging source/dest precompute (round 0) ----
    unsigned gx[2]; int dx[2];
#pragma unroll
    for (int i = 0; i < 2; ++i) {
        const int n = i * 512 + t;          // x chunk id 0..1023
        const int row = n >> 3, p = n & 7;
        const int c = p ^ ((n >> 6) & 7);   // logical chunk = pos ^ ((row>>3)&7)
        const unsigned col = (unsigned)((c >> 1) * 512 + (c & 1) * 4);  // floats
        gx[i] = (unsigned)(((unsigned)(row0 + row) * DD + col) * 4);    // bytes
        dx[i] = n * 4;                      // float offset in x region
    }
    unsigned gw; int dw;
    {
        const int n = t;                    // w chunk id 0..511
        const int e = n >> 3, p = n & 7;
        const int c = p ^ ((n >> 6) & 7);   // pos ^ (e>>3)
        const unsigned col = (unsigned)((c >> 1) * 512 + (c & 1) * 4);
        gw = (unsigned)(((unsigned)e * DD + col) * 4);
        dw = n * 4;
    }

#define STAGE(buf, round) do {                                                         \
    const unsigned ro_ = (unsigned)(round) * 32u;   /* 8 floats per round */           \
    float* bb_ = smem + (buf) * 6144;                                                  \
    _Pragma("unroll")                                                                  \
    for (int i_ = 0; i_ < 2; ++i_)                                                     \
        __builtin_amdgcn_global_load_lds(                                              \
            (const __attribute__((address_space(1))) void*)(xc + gx[i_] + ro_),        \
            (__attribute__((address_space(3))) void*)(bb_ + dx[i_]), 16, 0, 0);        \
    __builtin_amdgcn_global_load_lds(                                                  \
        (const __attribute__((address_space(1))) void*)(wc + gw + ro_),                \
        (__attribute__((address_space(3))) void*)(bb_ + 4096 + dw), 16, 0, 0);         \
} while (0)

    float acc[8][8];
#pragma unroll
    for (int i = 0; i < 8; ++i)
#pragma unroll
        for (int j = 0; j < 8; ++j) acc[i][j] = 0.f;

    int cur = 0;
    STAGE(0, 0);
    __syncthreads();

    for (int round = 0; round < ROUNDS; ++round) {
        if (round + 1 < ROUNDS) STAGE(cur ^ 1, round + 1);   // async prefetch
        const float4* bx = (const float4*)(smem + cur * 6144);
        const float4* bw = (const float4*)(smem + cur * 6144 + 4096);
#pragma unroll
        for (int k4 = 0; k4 < 2; ++k4) {
            const int px = (kq * 2 + k4) ^ (rg & 7);
            const int pw = (kq * 2 + k4) ^ eg;
            float4 xa[8], wv[8];
#pragma unroll
            for (int i = 0; i < 8; ++i) xa[i] = bx[(rg * 8 + i) * 8 + px];
#pragma unroll
            for (int j = 0; j < 8; ++j) wv[j] = bw[(eg * 8 + j) * 8 + pw];
#pragma unroll
            for (int i = 0; i < 8; ++i)
#pragma unroll
                for (int j = 0; j < 8; ++j) {
                    acc[i][j] = fmaf(xa[i].x, wv[j].x, acc[i][j]);
                    acc[i][j] = fmaf(xa[i].y, wv[j].y, acc[i][j]);
                    acc[i][j] = fmaf(xa[i].z, wv[j].z, acc[i][j]);
                    acc[i][j] = fmaf(xa[i].w, wv[j].w, acc[i][j]);
                }
        }
        __syncthreads();   // drain prefetch vmcnt + all waves done with cur
        cur ^= 1;
    }
#undef STAGE

    // ---- K-quarter merge through LDS (overlay staging memory) ----
    float* lg = smem;   // [128][65]
    if (kq == 0) {
#pragma unroll
        for (int i = 0; i < 8; ++i)
#pragma unroll
            for (int j = 0; j < 8; ++j)
                lg[(rg * 8 + i) * 65 + eg * 8 + j] = acc[i][j];
    }
    __syncthreads();
    for (int q = 1; q < 4; ++q) {
        if (kq == q) {
#pragma unroll
            for (int i = 0; i < 8; ++i)
#pragma unroll
                for (int j = 0; j < 8; ++j)
                    lg[(rg * 8 + i) * 65 + eg * 8 + j] += acc[i][j];
        }
        __syncthreads();
    }

    // ---- epilogue (512 threads, 128 rows) ----
    float* pm1    = smem + 8320;    // [4][128]
    float* pi1    = smem + 8832;
    float* pm2    = smem + 9344;
    float* pi2    = smem + 9856;
    float* rowm   = smem + 10368;   // [128]
    float* ps     = smem + 10496;   // [4][128]
    float* rowinv = smem + 11008;   // [128]
    float* cpart  = smem + 11136;   // [8][64]

    // Phase A: partial top-2 over 16 experts per thread (4 threads per row)
    {
        const int q = t >> 7, r = t & 127;
        float m1 = -INFINITY, m2 = -INFINITY, i1 = 0.f, i2 = 0.f;
        const float* rowp = lg + r * 65 + q * 16;
        for (int e = 0; e < 16; ++e) {
            const float v = rowp[e];
            if (v > m1)      { m2 = m1; i2 = i1; m1 = v; i1 = (float)(q * 16 + e); }
            else if (v > m2) { m2 = v; i2 = (float)(q * 16 + e); }
        }
        pm1[q * 128 + r] = m1; pi1[q * 128 + r] = i1;
        pm2[q * 128 + r] = m2; pi2[q * 128 + r] = i2;
    }
    __syncthreads();

    // Phase B: merge partials (index-ascending, strict > keeps lowest index)
    if (t < 128) {
        const int r = t;
        float m1 = pm1[r], m2 = pm2[r], i1 = pi1[r], i2 = pi2[r];
        for (int q = 1; q < 4; ++q) {
            const float b1 = pm1[q * 128 + r], b2 = pm2[q * 128 + r];
            const float bi1 = pi1[q * 128 + r], bi2 = pi2[q * 128 + r];
            if (b1 > m1) {
                if (m1 >= b2) { m2 = m1; i2 = i1; }
                else          { m2 = b2; i2 = bi2; }
                m1 = b1; i1 = bi1;
            } else if (b1 > m2) { m2 = b1; i2 = bi1; }
        }
        rowm[r] = m1;
        const float e2  = __expf(m2 - m1);
        const float inv = 1.0f / (1.0f + e2);
        const size_t gr = (size_t)row0 + r;
        out[2 * gr]     = inv;
        out[2 * gr + 1] = e2 * inv;
        out[2 * (size_t)NROWS + 2 * gr]     = i1;
        out[2 * (size_t)NROWS + 2 * gr + 1] = i2;
    }
    __syncthreads();

    // Phase C: partial exp-sums, stash exp() back into lg
    {
        const int q = t >> 7, r = t & 127;
        const float m = rowm[r];
        float s = 0.f;
        float* rowp = lg + r * 65 + q * 16;
        for (int e = 0; e < 16; ++e) {
            const float p = __expf(rowp[e] - m);
            rowp[e] = p;
            s += p;
        }
        ps[q * 128 + r] = s;
    }
    __syncthreads();

    // Phase D: row inverse sums
    if (t < 128)
        rowinv[t] = 1.0f / (ps[t] + ps[128 + t] + ps[256 + t] + ps[384 + t]);
    __syncthreads();

    // Phase E: partial column sums of router probs (16 rows per thread)
    {
        const int e = t & 63, q = t >> 6;   // q in 0..7
        float cs = 0.f;
        for (int rr = q * 16; rr < q * 16 + 16; ++rr)
            cs += lg[rr * 65 + e] * rowinv[rr];
        cpart[q * 64 + e] = cs;
    }
    __syncthreads();

    // Phase F: one atomic per expert per block
    if (t < 64) {
        float s = 0.f;
#pragma unroll
        for (int q = 0; q < 8; ++q) s += cpart[q * 64 + t];
        atomicAdd(&accum[t], s);
    }
}

// ---------------------------------------------------------------------------
// Finisher: expert_probs = accum / NROWS; lb_loss = .01 * sum(p*log(p+1e-8))
// ---------------------------------------------------------------------------
__global__ void router_loss(const float* __restrict__ accum, float* __restrict__ out) {
    const int e = threadIdx.x;  // 64 threads = 1 wave
    const float p = accum[e] * (1.0f / (float)NROWS);
    float v = p * __logf(p + 1e-8f);
#pragma unroll
    for (int off = 32; off > 0; off >>= 1) v += __shfl_down(v, off);
    if (e == 0) out[4 * (size_t)NROWS] = 0.01f * v;
}

extern "C" void kernel_launch(void* const* d_in, const int* in_sizes, int n_in,
                              void* d_out, int out_size, void* d_ws, size_t ws_size,
                              hipStream_t stream) {
    const float* x = (const float*)d_in[0];
    const float* W = (const float*)d_in[1];
    float* out = (float*)d_out;
    float* accum = (float*)d_ws;

    hipMemsetAsync(d_ws, 0, EE * sizeof(float), stream);
    router_main<<<NROWS / BR, 512, 0, stream>>>(x, W, out, accum);
    router_loss<<<1, 64, 0, stream>>>(accum, out);
}